// Round 19
// baseline (290.602 us; speedup 1.0000x reference)
//
#include <hip/hip_runtime.h>
#include <math.h>

#define D_ 128
#define H_ 160
#define W_ 160
#define HW_ (H_ * W_)            // 25600
#define V_ (D_ * H_ * W_)        // 3,276,800
#define SMOOTHF 1e-5

#define R_ 16                    // rows covered per block (TY + 6 halo)
#define TY 10                    // output rows per block
#define ZC 32                    // z-planes produced per block
#define COLS 40                  // float4 columns (W_/4)
#define NT 640                   // R_ * COLS threads (10 waves)
#define LROW 41                  // padded row length in float4 (164 floats)
#define NYT 16                   // H_/TY
#define NZC 4                    // D_/ZC
#define NTB (NYT * NZC)          // 64 tiles per volume

__device__ __forceinline__ float max3f(float a, float b, float c) { return fmaxf(fmaxf(a, b), c); }
__device__ __forceinline__ float min3f(float a, float b, float c) { return fminf(fminf(a, b), c); }
__device__ __forceinline__ float4 f4min(float4 a, float4 b) {
    return make_float4(fminf(a.x,b.x), fminf(a.y,b.y), fminf(a.z,b.z), fminf(a.w,b.w));
}
__device__ __forceinline__ float4 f4max(float4 a, float4 b) {
    return make_float4(fmaxf(a.x,b.x), fmaxf(a.y,b.y), fmaxf(a.z,b.z), fmaxf(a.w,b.w));
}
// sliding 3-window min/max along x of (l | c | r)
__device__ __forceinline__ float4 min3x(float l, float4 c, float r) {
    return make_float4(min3f(l,c.x,c.y), min3f(c.x,c.y,c.z), min3f(c.y,c.z,c.w), min3f(c.z,c.w,r));
}
__device__ __forceinline__ float4 max3x(float l, float4 c, float r) {
    return make_float4(max3f(l,c.x,c.y), max3f(c.x,c.y,c.z), max3f(c.y,c.z,c.w), max3f(c.z,c.w,r));
}
__device__ __forceinline__ float4 relu4sub(float4 a, float4 b) {   // relu(a-b)
    return make_float4(fmaxf(a.x-b.x,0.f), fmaxf(a.y-b.y,0.f), fmaxf(a.z-b.z,0.f), fmaxf(a.w-b.w,0.f));
}
__device__ __forceinline__ float4 skel_upd(float4 s, float4 d) {   // s + relu(d - s*d)
    return make_float4(s.x + fmaxf(d.x - s.x*d.x, 0.f), s.y + fmaxf(d.y - s.y*d.y, 0.f),
                       s.z + fmaxf(d.z - s.z*d.z, 0.f), s.w + fmaxf(d.w - s.w*d.w, 0.f));
}

// ---- bf16 pack/unpack (RNE). Intermediates e2/skel stored as bf16 to halve
// the A-write / B-read byte volume (R19). ±INF survives exactly; inputs have
// no NaN. Error ~2e-3 relative on intermediates -> final loss err ~1e-3,
// threshold 1.2e-2.
__device__ __forceinline__ unsigned bf16rne(float x) {
    unsigned u = __float_as_uint(x);
    return (u + 0x7FFFu + ((u >> 16) & 1u)) >> 16;
}
__device__ __forceinline__ uint2 pack_bf16x4(float4 v) {
    uint2 o;
    o.x = bf16rne(v.x) | (bf16rne(v.y) << 16);
    o.y = bf16rne(v.z) | (bf16rne(v.w) << 16);
    return o;
}
__device__ __forceinline__ float4 unpack_bf16x4(uint2 p) {
    return make_float4(__uint_as_float(p.x << 16),
                       __uint_as_float(p.x & 0xFFFF0000u),
                       __uint_as_float(p.y << 16),
                       __uint_as_float(p.y & 0xFFFF0000u));
}

// LDS-only barrier (R14, helped): ring hazards need only LDS ordering;
// global loads/stores stay in flight across steps.
__device__ __forceinline__ void block_sync_lds() {
    asm volatile("s_waitcnt lgkmcnt(0)" ::: "memory");
    __builtin_amdgcn_s_barrier();
    asm volatile("" ::: "memory");
}

// vol i in 0..7: 0..3 = pred (b=i>>1, ch=(i&1)+1), 4..7 = gt one-hot
__device__ __forceinline__ float4 load_src4(const float* __restrict__ net,
                                            const int* __restrict__ tgt,
                                            int i, long p) {
    if (i < 4) {
        int b = i >> 1, c = (i & 1) + 1;
        return *(const float4*)(net + (long)(b * 3 + c) * V_ + p);
    } else {
        int j = i - 4;
        int b = j >> 1, c = (j & 1) + 1;
        int4 t = *(const int4*)(tgt + (long)b * V_ + p);
        float4 o;
        int tx = t.x < 0 ? 0 : (t.x > 2 ? 2 : t.x);
        int ty = t.y < 0 ? 0 : (t.y > 2 ? 2 : t.y);
        int tz = t.z < 0 ? 0 : (t.z > 2 ? 2 : t.z);
        int tw = t.w < 0 ? 0 : (t.w > 2 ? 2 : t.w);
        o.x = (tx == c) ? 1.0f : 0.0f;
        o.y = (ty == c) ? 1.0f : 0.0f;
        o.z = (tz == c) ? 1.0f : 0.0f;
        o.w = (tw == c) ? 1.0f : 0.0f;
        return o;
    }
}

// Two skeleton iterations fused, thread-per-column z-march, single LDS-only
// barrier/step, all global loads issued at step top, XCD swizzle (R17 best:
// 277.7us). R19 change: e2/skel intermediates stored bf16-packed (uint2 per
// float4) -> A writes 205->102 MB, B reads 180->~95 MB. LDS + stencil math
// stay fp32/float4 (unpack at load, pack at store). Dropped: s_sleep (R18
// null), unroll-2 (R15 null; frees VGPR headroom for pack temps).
// __launch_bounds__: VGPR must stay <= 64 (R8: (NT,7) cap-36 spilled).
// Tripwire: kernel-B WRITE_SIZE must stay ~KB (spill detector).
template <int VAR>
__global__ __launch_bounds__(NT, 4) void fused_pair(
    const float* __restrict__ net, const int* __restrict__ tgt, int i0,
    const uint2* __restrict__ e_in, uint2* __restrict__ e_out,
    uint2* __restrict__ skel, float* __restrict__ partials) {

    __shared__ float4 Pb[2][R_ * LROW];
    __shared__ float4 E1b[2][R_ * LROW];
    __shared__ float4 E2b[2][R_ * LROW];
    __shared__ float smr[NT / 64][2];

    const int j = blockIdx.y, i = i0 + j;
    const int bxr = blockIdx.x;
    const int bx = ((bxr & 7) << 3) | (bxr >> 3);   // T1 XCD swizzle, bijective on [0,64)
    const int y0 = (bx % NYT) * TY;
    const int z0 = (bx / NYT) * ZC;
    const int tid = threadIdx.x;
    const int r  = tid / COLS;         // 0..15
    const int x4 = tid - r * COLS;     // 0..39
    const int y  = y0 - 3 + r;
    const bool yok  = (y >= 0 && y < H_);
    const bool ymok = (y - 1 >= 0 && y - 1 < H_);
    const bool ypok = (y + 1 >= 0 && y + 1 < H_);
    const int rm = (r > 0) ? r - 1 : 0;
    const int rp = (r < R_ - 1) ? r + 1 : R_ - 1;
    const int xm = (x4 > 0) ? x4 - 1 : 0;
    const int xp = (x4 < COLS - 1) ? x4 + 1 : COLS - 1;
    const bool fxm = (x4 > 0), fxp = (x4 < COLS - 1);
    const bool rout = (r >= 3 && r < 3 + TY);
    const long colbase = (long)(yok ? y : 0) * W_ + x4 * 4;

    const uint2* ein_v = (VAR == 1) ? e_in + (long)j * (V_ / 4) : nullptr;
    uint2* eout_v = (VAR == 0) ? e_out + (long)j * (V_ / 4) : nullptr;
    uint2* skel_v = skel + (long)j * (V_ / 4);
    const int ipart = (i < 4) ? (i + 4) : (i - 4);

    const float4 INF4  = make_float4( INFINITY,  INFINITY,  INFINITY,  INFINITY);
    const float4 NINF4 = make_float4(-INFINITY, -INFINITY, -INFINITY, -INFINITY);

    // register rings (per-thread column)
    float4 p1 = INF4, p2 = INF4;                      // P(s-1), P(s-2)
    float4 b1 = NINF4, b2 = NINF4, b3 = NINF4;        // e1(s-2), e1(s-3), e1(s-4)
    float4 c1 = NINF4;                                // e2(s-3)
    float4 x1a = NINF4, x1b = NINF4, x1c = NINF4;     // xym1(s-5), (s-4), (s-3)
    float4 x2a = NINF4, x2b = NINF4;                  // xym2(s-5), (s-4)
    float acc0 = 0.f, acc1 = 0.f;

    // prefetch first plane (s = z0-3)
    float4 a_inflight = INF4;
    {
        const int sf = z0 - 3;
        if (sf >= 0 && sf < D_ && yok) {
            long p = (long)sf * HW_ + colbase;
            a_inflight = (VAR == 0) ? load_src4(net, tgt, i, p)
                                    : unpack_bf16x4(ein_v[p >> 2]);
        }
    }

    for (int s = z0 - 3; s <= z0 + ZC + 3; ++s) {
        // ---- W0a: publish prefetched plane s to Pb[s&1]
        float4 anew = a_inflight;
        if (s <= z0 + ZC + 2) {
            Pb[s & 1][r * LROW + x4] = anew;
        }
        // ---- W0b: issue load of plane s+1
        {
            const int sn = s + 1;
            float4 v = INF4;
            if (sn <= z0 + ZC + 2 && sn >= 0 && sn < D_ && yok) {
                long p = (long)sn * HW_ + colbase;
                v = (VAR == 0) ? load_src4(net, tgt, i, p)
                               : unpack_bf16x4(ein_v[p >> 2]);
            }
            a_inflight = v;
        }
        // ---- W0c: issue OUT-plane loads for z = s-4 (consumed at OUT below)
        const int zo = s - 4;
        const bool outok = (zo >= z0 && zo < z0 + ZC && rout);
        const long po = (long)(outok ? zo : z0) * HW_ + colbase;
        const long pq = po >> 2;
        float4 cin_o = INF4, psk_o = make_float4(0,0,0,0), ppr_o = make_float4(0,0,0,0);
        if (outok) {
            if (VAR == 0) {
                cin_o = load_src4(net, tgt, i, po);        // src(zo)
            } else {
                cin_o = unpack_bf16x4(ein_v[pq]);          // e2(zo)
                psk_o = unpack_bf16x4(skel_v[pq]);         // skel(zo)
                ppr_o = load_src4(net, tgt, ipart, po);    // partner(zo)
            }
        }

        // ---- W1: e1(s-1) = 7-pt cross erode (reads Pb plane s-1, prev step)
        float4 fe1 = NINF4;
        if (s >= z0 - 1 && s <= z0 + ZC + 2) {
            const int z1 = s - 1;
            const bool z1ok = (z1 >= 0 && z1 < D_);
            const float4* Pp = Pb[z1 & 1];
            float4 up = Pp[rm * LROW + x4];
            float4 dn = Pp[rp * LROW + x4];
            float lf = Pp[r * LROW + xm].w;
            float rt = Pp[r * LROW + xp].x;
            if (!ymok) up = INF4;
            if (!ypok) dn = INF4;
            if (!fxm) lf = INFINITY;
            if (!fxp) rt = INFINITY;
            float4 e = f4min(f4min(min3x(lf, p1, rt), f4min(up, dn)), f4min(p2, anew));
            if (!z1ok || !yok) e = NINF4;
            fe1 = e;
            E1b[z1 & 1][r * LROW + x4] = e;
        }

        // ---- W2: e2(s-2) + xym1(s-2)  (reads E1b plane s-2, prev step)
        float4 fe2 = NINF4, f1 = NINF4;
        if (s >= z0 + 1 && s <= z0 + ZC + 2) {
            const int z2 = s - 2;
            const bool z2ok = (z2 >= 0 && z2 < D_);
            const float4* Ep = E1b[z2 & 1];
            float4 n01 = Ep[rm * LROW + x4];
            float4 n21 = Ep[rp * LROW + x4];
            float4 c = b1;                          // e1(s-2) own column
            float l0 = fxm ? Ep[rm * LROW + xm].w : -INFINITY;
            float r0 = fxp ? Ep[rm * LROW + xp].x : -INFINITY;
            float l1 = fxm ? Ep[r  * LROW + xm].w : -INFINITY;
            float r1 = fxp ? Ep[r  * LROW + xp].x : -INFINITY;
            float l2 = fxm ? Ep[rp * LROW + xm].w : -INFINITY;
            float r2 = fxp ? Ep[rp * LROW + xp].x : -INFINITY;
            // erode cross (min identities = +INF)
            {
                float4 up = ymok ? n01 : INF4;
                float4 dn = ypok ? n21 : INF4;
                float lf = fxm ? l1 : INFINITY;
                float rt = fxp ? r1 : INFINITY;
                float4 zu = (z2 >= 1)     ? b2  : INF4;   // e1(s-3)
                float4 zd = (z2 + 1 < D_) ? fe1 : INF4;   // e1(s-1), this step
                float4 e = f4min(f4min(min3x(lf, c, rt), f4min(up, dn)), f4min(zu, zd));
                if (!z2ok || !yok) e = NINF4;
                fe2 = e;
            }
            // xym1(s-2): 3x3 xy-max of e1 (pad rows already -INF in LDS)
            {
                float4 m = f4max(f4max(max3x(l0, n01, r0), max3x(l1, c, r1)), max3x(l2, n21, r2));
                if (!z2ok) m = NINF4;
                f1 = m;
            }
            E2b[z2 & 1][r * LROW + x4] = fe2;
            if (VAR == 0 && z2 >= z0 && z2 < z0 + ZC && rout) {
                eout_v[((long)z2 * HW_ + colbase) >> 2] = pack_bf16x4(fe2);
            }
        }

        // ---- W3: xym2(s-3)  (reads E2b plane s-3, prev step)
        float4 f2 = NINF4;
        if (s >= z0 + 2) {
            const int z3 = s - 3;
            const float4* Eq = E2b[z3 & 1];
            float4 m01 = Eq[rm * LROW + x4];
            float4 m21 = Eq[rp * LROW + x4];
            float l0 = fxm ? Eq[rm * LROW + xm].w : -INFINITY;
            float r0 = fxp ? Eq[rm * LROW + xp].x : -INFINITY;
            float l1 = fxm ? Eq[r  * LROW + xm].w : -INFINITY;
            float r1 = fxp ? Eq[r  * LROW + xp].x : -INFINITY;
            float l2 = fxm ? Eq[rp * LROW + xm].w : -INFINITY;
            float r2 = fxp ? Eq[rp * LROW + xp].x : -INFINITY;
            f2 = f4max(f4max(max3x(l0, m01, r0), max3x(l1, c1, r1)), max3x(l2, m21, r2));
        }

        // ---- OUT: plane z = s-4 (uses W0c-prefetched cin_o/psk_o/ppr_o)
        if (outok) {
            float4 dil1 = f4max(f4max(x1a, x1b), x1c);     // xym1(z-1..z+1)
            float4 dil2 = f4max(f4max(x2a, x2b), f2);      // xym2(z-1..z+1)
            float4 ce1 = b3;                               // e1(z)
            if (VAR == 0) {
                float4 s0 = relu4sub(cin_o, dil1);         // relu(src - dil(e1))
                float4 d1 = relu4sub(ce1, dil2);           // relu(e1 - dil(e2))
                skel_v[pq] = pack_bf16x4(skel_upd(s0, d1));
            } else {
                float4 d2 = relu4sub(cin_o, dil1);         // relu(e2 - dil(e3))
                float4 sp = skel_upd(psk_o, d2);
                float4 d3 = relu4sub(ce1, dil2);           // relu(e3 - dil(e4))
                float4 fin = skel_upd(sp, d3);
                acc0 += fin.x * ppr_o.x + fin.y * ppr_o.y + fin.z * ppr_o.z + fin.w * ppr_o.w;
                acc1 += fin.x + fin.y + fin.z + fin.w;
            }
        }

        // ---- ring shifts
        p2 = p1; p1 = anew;
        b3 = b2; b2 = b1; b1 = fe1;
        c1 = fe2;
        x1a = x1b; x1b = x1c; x1c = f1;
        x2a = x2b; x2b = f2;

        block_sync_lds();   // LDS-only barrier: RAW+WAR for Pb/E1b/E2b rings
    }

    if (VAR == 1) {
        #pragma unroll
        for (int off = 32; off > 0; off >>= 1) {
            acc0 += __shfl_down(acc0, off);
            acc1 += __shfl_down(acc1, off);
        }
        int wid = tid >> 6, lane = tid & 63;
        __syncthreads();
        if (lane == 0) { smr[wid][0] = acc0; smr[wid][1] = acc1; }
        __syncthreads();
        if (tid == 0) {
            float t0 = 0.f, t1 = 0.f;
            #pragma unroll
            for (int w = 0; w < NT / 64; ++w) { t0 += smr[w][0]; t1 += smr[w][1]; }
            long base = ((long)i * NTB + bx) * 2;
            partials[base + 0] = t0;
            partials[base + 1] = t1;
        }
    }
}

// one block (64 threads) per volume: sum NTB=64 partial pairs in double
__global__ void reduce_partials_kernel(const float* __restrict__ partials,
                                       int i0,
                                       double* __restrict__ sums) {
    int i = i0 + blockIdx.x;
    int t = threadIdx.x;    // 64
    long base = ((long)i * NTB + t) * 2;
    double v0 = (double)partials[base + 0];
    double v1 = (double)partials[base + 1];
    #pragma unroll
    for (int off = 32; off > 0; off >>= 1) {
        v0 += __shfl_down(v0, off);
        v1 += __shfl_down(v1, off);
    }
    if (t == 0) {
        sums[2 * i + 0] = v0;
        sums[2 * i + 1] = v1;
    }
}

__global__ void finalize_kernel(const double* __restrict__ sums,
                                float* __restrict__ out) {
    if (threadIdx.x == 0 && blockIdx.x == 0) {
        double acc = 0.0;
        #pragma unroll
        for (int i = 0; i < 4; ++i) {
            double tprec = (sums[2 * i + 0] + SMOOTHF) / (sums[2 * i + 1] + SMOOTHF);
            double tsens = (sums[2 * (i + 4) + 0] + SMOOTHF) / (sums[2 * (i + 4) + 1] + SMOOTHF);
            double cl = (2.0 * tprec * tsens + SMOOTHF) / (tprec + tsens + SMOOTHF);
            acc += cl;
        }
        out[0] = (float)(1.0 - acc * 0.25);
    }
}

extern "C" void kernel_launch(void* const* d_in, const int* in_sizes, int n_in,
                              void* d_out, int out_size, void* d_ws, size_t ws_size,
                              hipStream_t stream) {
    const float* net = (const float*)d_in[0];
    const int* tgt = (const int*)d_in[1];
    float* out = (float*)d_out;

    char* ws = (char*)d_ws;
    double* sums = (double*)ws;                      // 16 doubles
    float* partials = (float*)(ws + 256);            // 8*NTB*2 floats
    size_t head = 256 + (size_t)8 * NTB * 2 * sizeof(float);
    head = (head + 255) & ~(size_t)255;

    // bf16-packed intermediates: per volume, SKEL = 2*V_ bytes, E2 = 2*V_ bytes
    size_t perVol = (size_t)4 * V_;                  // both arrays, bytes
    int G = 1;
    if (ws_size >= head + perVol * 8) G = 8;
    else if (ws_size >= head + perVol * 4) G = 4;
    else if (ws_size >= head + perVol * 2) G = 2;

    uint2* SKEL = (uint2*)(ws + head);
    uint2* E2buf = SKEL + (size_t)G * (V_ / 4);

    dim3 blk(NT);
    dim3 grd(NTB, G);

    for (int i0 = 0; i0 < 8; i0 += G) {
        // A: src -> e2 volume (bf16) + skel (bf16) (iterations 0,1)
        fused_pair<0><<<grd, blk, 0, stream>>>(net, tgt, i0, nullptr, E2buf, SKEL, nullptr);
        // B: e2 -> (e3,e4 in LDS/regs), final skel in-register, reduce
        fused_pair<1><<<grd, blk, 0, stream>>>(net, tgt, i0, E2buf, nullptr, SKEL, partials);

        reduce_partials_kernel<<<G, 64, 0, stream>>>(partials, i0, sums);
    }

    finalize_kernel<<<1, 64, 0, stream>>>(sums, out);
}

// Round 20
// 277.602 us; speedup vs baseline: 1.0468x; 1.0468x over previous
//
#include <hip/hip_runtime.h>
#include <math.h>

#define D_ 128
#define H_ 160
#define W_ 160
#define HW_ (H_ * W_)            // 25600
#define V_ (D_ * H_ * W_)        // 3,276,800
#define SMOOTHF 1e-5

#define R_ 16                    // rows covered per block (TY + 6 halo)
#define TY 10                    // output rows per block
#define ZC 32                    // z-planes produced per block
#define COLS 40                  // float4 columns (W_/4)
#define NT 640                   // R_ * COLS threads (10 waves)
#define LROW 41                  // padded row length in float4 (164 floats)
#define NYT 16                   // H_/TY
#define NZC 4                    // D_/ZC
#define NTB (NYT * NZC)          // 64 tiles per volume

__device__ __forceinline__ float max3f(float a, float b, float c) { return fmaxf(fmaxf(a, b), c); }
__device__ __forceinline__ float min3f(float a, float b, float c) { return fminf(fminf(a, b), c); }
__device__ __forceinline__ float4 f4min(float4 a, float4 b) {
    return make_float4(fminf(a.x,b.x), fminf(a.y,b.y), fminf(a.z,b.z), fminf(a.w,b.w));
}
__device__ __forceinline__ float4 f4max(float4 a, float4 b) {
    return make_float4(fmaxf(a.x,b.x), fmaxf(a.y,b.y), fmaxf(a.z,b.z), fmaxf(a.w,b.w));
}
// sliding 3-window min/max along x of (l | c | r)
__device__ __forceinline__ float4 min3x(float l, float4 c, float r) {
    return make_float4(min3f(l,c.x,c.y), min3f(c.x,c.y,c.z), min3f(c.y,c.z,c.w), min3f(c.z,c.w,r));
}
__device__ __forceinline__ float4 max3x(float l, float4 c, float r) {
    return make_float4(max3f(l,c.x,c.y), max3f(c.x,c.y,c.z), max3f(c.y,c.z,c.w), max3f(c.z,c.w,r));
}
__device__ __forceinline__ float4 relu4sub(float4 a, float4 b) {   // relu(a-b)
    return make_float4(fmaxf(a.x-b.x,0.f), fmaxf(a.y-b.y,0.f), fmaxf(a.z-b.z,0.f), fmaxf(a.w-b.w,0.f));
}
__device__ __forceinline__ float4 skel_upd(float4 s, float4 d) {   // s + relu(d - s*d)
    return make_float4(s.x + fmaxf(d.x - s.x*d.x, 0.f), s.y + fmaxf(d.y - s.y*d.y, 0.f),
                       s.z + fmaxf(d.z - s.z*d.z, 0.f), s.w + fmaxf(d.w - s.w*d.w, 0.f));
}

// LDS-only barrier (R14, helped): __syncthreads() drains vmcnt(0) each step,
// forcing kernel A's late-issued stores to retire on the critical path.
// Ring hazards only need LDS ordering: lgkmcnt(0) + s_barrier.
__device__ __forceinline__ void block_sync_lds() {
    asm volatile("s_waitcnt lgkmcnt(0)" ::: "memory");
    __builtin_amdgcn_s_barrier();
    asm volatile("" ::: "memory");
}

// vol i in 0..7: 0..3 = pred (b=i>>1, ch=(i&1)+1), 4..7 = gt one-hot
__device__ __forceinline__ float4 load_src4(const float* __restrict__ net,
                                            const int* __restrict__ tgt,
                                            int i, long p) {
    if (i < 4) {
        int b = i >> 1, c = (i & 1) + 1;
        return *(const float4*)(net + (long)(b * 3 + c) * V_ + p);
    } else {
        int j = i - 4;
        int b = j >> 1, c = (j & 1) + 1;
        int4 t = *(const int4*)(tgt + (long)b * V_ + p);
        float4 o;
        int tx = t.x < 0 ? 0 : (t.x > 2 ? 2 : t.x);
        int ty = t.y < 0 ? 0 : (t.y > 2 ? 2 : t.y);
        int tz = t.z < 0 ? 0 : (t.z > 2 ? 2 : t.z);
        int tw = t.w < 0 ? 0 : (t.w > 2 ? 2 : t.w);
        o.x = (tx == c) ? 1.0f : 0.0f;
        o.y = (ty == c) ? 1.0f : 0.0f;
        o.z = (tz == c) ? 1.0f : 0.0f;
        o.w = (tw == c) ? 1.0f : 0.0f;
        return o;
    }
}

// Two skeleton iterations fused, thread-per-column z-march, single LDS-only
// barrier/step, all global loads issued at step top. EXACT R17 kernel
// (session best: 277.7us). R19's bf16 intermediates regressed (+13us,
// VALUBusy 46->59%): the kernel is VALU-issue/dependency-bound, not
// memory-bound — halving bytes while adding pack/unpack VALU lost.
// R18's phase-stagger was null. This is the verified-floor configuration:
//   - 2-slot LDS parity rings, 1 LDS-only barrier/step (R11/R14)
//   - main-plane + OUT-plane software prefetch at step top (R12/R13)
//   - XCD-aware bx swizzle, bijective on 64 (R17: FETCH -36%)
//   - fp32 intermediates, float4 LDS, unroll-2 (R15 neutral, keeps VGPR=64)
// __launch_bounds__: VGPR must stay <= 64 (R8: (NT,7) cap-36 spilled).
// Tripwire: kernel-B WRITE_SIZE must stay ~KB (spill detector).
template <int VAR>
__global__ __launch_bounds__(NT, 4) void fused_pair(
    const float* __restrict__ net, const int* __restrict__ tgt, int i0,
    const float* __restrict__ e_in, float* __restrict__ e_out,
    float* __restrict__ skel, float* __restrict__ partials) {

    __shared__ float4 Pb[2][R_ * LROW];
    __shared__ float4 E1b[2][R_ * LROW];
    __shared__ float4 E2b[2][R_ * LROW];
    __shared__ float smr[NT / 64][2];

    const int j = blockIdx.y, i = i0 + j;
    const int bxr = blockIdx.x;
    const int bx = ((bxr & 7) << 3) | (bxr >> 3);   // T1 XCD swizzle, bijective on [0,64)
    const int y0 = (bx % NYT) * TY;
    const int z0 = (bx / NYT) * ZC;
    const int tid = threadIdx.x;
    const int r  = tid / COLS;         // 0..15
    const int x4 = tid - r * COLS;     // 0..39
    const int y  = y0 - 3 + r;
    const bool yok  = (y >= 0 && y < H_);
    const bool ymok = (y - 1 >= 0 && y - 1 < H_);
    const bool ypok = (y + 1 >= 0 && y + 1 < H_);
    const int rm = (r > 0) ? r - 1 : 0;
    const int rp = (r < R_ - 1) ? r + 1 : R_ - 1;
    const int xm = (x4 > 0) ? x4 - 1 : 0;
    const int xp = (x4 < COLS - 1) ? x4 + 1 : COLS - 1;
    const bool fxm = (x4 > 0), fxp = (x4 < COLS - 1);
    const bool rout = (r >= 3 && r < 3 + TY);
    const long colbase = (long)(yok ? y : 0) * W_ + x4 * 4;

    const float* ein_v = (VAR == 1) ? e_in + (long)j * V_ : nullptr;
    float* eout_v = (VAR == 0) ? e_out + (long)j * V_ : nullptr;
    float* skel_v = skel + (long)j * V_;
    const int ipart = (i < 4) ? (i + 4) : (i - 4);

    const float4 INF4  = make_float4( INFINITY,  INFINITY,  INFINITY,  INFINITY);
    const float4 NINF4 = make_float4(-INFINITY, -INFINITY, -INFINITY, -INFINITY);

    // register rings (per-thread column)
    float4 p1 = INF4, p2 = INF4;                      // P(s-1), P(s-2)
    float4 b1 = NINF4, b2 = NINF4, b3 = NINF4;        // e1(s-2), e1(s-3), e1(s-4)
    float4 c1 = NINF4;                                // e2(s-3)
    float4 x1a = NINF4, x1b = NINF4, x1c = NINF4;     // xym1(s-5), (s-4), (s-3)
    float4 x2a = NINF4, x2b = NINF4;                  // xym2(s-5), (s-4)
    float acc0 = 0.f, acc1 = 0.f;

    // prefetch first plane (s = z0-3)
    float4 a_inflight = INF4;
    {
        const int sf = z0 - 3;
        if (sf >= 0 && sf < D_ && yok) {
            long p = (long)sf * HW_ + colbase;
            a_inflight = (VAR == 0) ? load_src4(net, tgt, i, p)
                                    : *(const float4*)(ein_v + p);
        }
    }

    #pragma unroll 2
    for (int s = z0 - 3; s <= z0 + ZC + 3; ++s) {
        // ---- W0a: publish prefetched plane s to Pb[s&1]
        float4 anew = a_inflight;
        if (s <= z0 + ZC + 2) {
            Pb[s & 1][r * LROW + x4] = anew;
        }
        // ---- W0b: issue load of plane s+1
        {
            const int sn = s + 1;
            float4 v = INF4;
            if (sn <= z0 + ZC + 2 && sn >= 0 && sn < D_ && yok) {
                long p = (long)sn * HW_ + colbase;
                v = (VAR == 0) ? load_src4(net, tgt, i, p)
                               : *(const float4*)(ein_v + p);
            }
            a_inflight = v;
        }
        // ---- W0c: issue OUT-plane loads for z = s-4 (consumed at OUT below)
        const int zo = s - 4;
        const bool outok = (zo >= z0 && zo < z0 + ZC && rout);
        const long po = (long)(outok ? zo : z0) * HW_ + colbase;
        float4 cin_o = INF4, psk_o = make_float4(0,0,0,0), ppr_o = make_float4(0,0,0,0);
        if (outok) {
            if (VAR == 0) {
                cin_o = load_src4(net, tgt, i, po);        // src(zo)
            } else {
                cin_o = *(const float4*)(ein_v + po);      // e2(zo)
                psk_o = *(const float4*)(skel_v + po);     // skel(zo)
                ppr_o = load_src4(net, tgt, ipart, po);    // partner(zo)
            }
        }

        // ---- W1: e1(s-1) = 7-pt cross erode (reads Pb plane s-1, prev step)
        float4 fe1 = NINF4;
        if (s >= z0 - 1 && s <= z0 + ZC + 2) {
            const int z1 = s - 1;
            const bool z1ok = (z1 >= 0 && z1 < D_);
            const float4* Pp = Pb[z1 & 1];
            float4 up = Pp[rm * LROW + x4];
            float4 dn = Pp[rp * LROW + x4];
            float lf = Pp[r * LROW + xm].w;
            float rt = Pp[r * LROW + xp].x;
            if (!ymok) up = INF4;
            if (!ypok) dn = INF4;
            if (!fxm) lf = INFINITY;
            if (!fxp) rt = INFINITY;
            float4 e = f4min(f4min(min3x(lf, p1, rt), f4min(up, dn)), f4min(p2, anew));
            if (!z1ok || !yok) e = NINF4;
            fe1 = e;
            E1b[z1 & 1][r * LROW + x4] = e;
        }

        // ---- W2: e2(s-2) + xym1(s-2)  (reads E1b plane s-2, prev step)
        float4 fe2 = NINF4, f1 = NINF4;
        if (s >= z0 + 1 && s <= z0 + ZC + 2) {
            const int z2 = s - 2;
            const bool z2ok = (z2 >= 0 && z2 < D_);
            const float4* Ep = E1b[z2 & 1];
            float4 n01 = Ep[rm * LROW + x4];
            float4 n21 = Ep[rp * LROW + x4];
            float4 c = b1;                          // e1(s-2) own column
            float l0 = fxm ? Ep[rm * LROW + xm].w : -INFINITY;
            float r0 = fxp ? Ep[rm * LROW + xp].x : -INFINITY;
            float l1 = fxm ? Ep[r  * LROW + xm].w : -INFINITY;
            float r1 = fxp ? Ep[r  * LROW + xp].x : -INFINITY;
            float l2 = fxm ? Ep[rp * LROW + xm].w : -INFINITY;
            float r2 = fxp ? Ep[rp * LROW + xp].x : -INFINITY;
            // erode cross (min identities = +INF)
            {
                float4 up = ymok ? n01 : INF4;
                float4 dn = ypok ? n21 : INF4;
                float lf = fxm ? l1 : INFINITY;
                float rt = fxp ? r1 : INFINITY;
                float4 zu = (z2 >= 1)     ? b2  : INF4;   // e1(s-3)
                float4 zd = (z2 + 1 < D_) ? fe1 : INF4;   // e1(s-1), this step
                float4 e = f4min(f4min(min3x(lf, c, rt), f4min(up, dn)), f4min(zu, zd));
                if (!z2ok || !yok) e = NINF4;
                fe2 = e;
            }
            // xym1(s-2): 3x3 xy-max of e1 (pad rows already -INF in LDS)
            {
                float4 m = f4max(f4max(max3x(l0, n01, r0), max3x(l1, c, r1)), max3x(l2, n21, r2));
                if (!z2ok) m = NINF4;
                f1 = m;
            }
            E2b[z2 & 1][r * LROW + x4] = fe2;
            if (VAR == 0 && z2 >= z0 && z2 < z0 + ZC && rout) {
                *(float4*)(eout_v + (long)z2 * HW_ + colbase) = fe2;
            }
        }

        // ---- W3: xym2(s-3)  (reads E2b plane s-3, prev step)
        float4 f2 = NINF4;
        if (s >= z0 + 2) {
            const int z3 = s - 3;
            const float4* Eq = E2b[z3 & 1];
            float4 m01 = Eq[rm * LROW + x4];
            float4 m21 = Eq[rp * LROW + x4];
            float l0 = fxm ? Eq[rm * LROW + xm].w : -INFINITY;
            float r0 = fxp ? Eq[rm * LROW + xp].x : -INFINITY;
            float l1 = fxm ? Eq[r  * LROW + xm].w : -INFINITY;
            float r1 = fxp ? Eq[r  * LROW + xp].x : -INFINITY;
            float l2 = fxm ? Eq[rp * LROW + xm].w : -INFINITY;
            float r2 = fxp ? Eq[rp * LROW + xp].x : -INFINITY;
            f2 = f4max(f4max(max3x(l0, m01, r0), max3x(l1, c1, r1)), max3x(l2, m21, r2));
        }

        // ---- OUT: plane z = s-4 (uses W0c-prefetched cin_o/psk_o/ppr_o)
        if (outok) {
            float4 dil1 = f4max(f4max(x1a, x1b), x1c);     // xym1(z-1..z+1)
            float4 dil2 = f4max(f4max(x2a, x2b), f2);      // xym2(z-1..z+1)
            float4 ce1 = b3;                               // e1(z)
            if (VAR == 0) {
                float4 s0 = relu4sub(cin_o, dil1);         // relu(src - dil(e1))
                float4 d1 = relu4sub(ce1, dil2);           // relu(e1 - dil(e2))
                *(float4*)(skel_v + po) = skel_upd(s0, d1);
            } else {
                float4 d2 = relu4sub(cin_o, dil1);         // relu(e2 - dil(e3))
                float4 sp = skel_upd(psk_o, d2);
                float4 d3 = relu4sub(ce1, dil2);           // relu(e3 - dil(e4))
                float4 fin = skel_upd(sp, d3);
                acc0 += fin.x * ppr_o.x + fin.y * ppr_o.y + fin.z * ppr_o.z + fin.w * ppr_o.w;
                acc1 += fin.x + fin.y + fin.z + fin.w;
            }
        }

        // ---- ring shifts (renamed away by unroll-2 copy propagation)
        p2 = p1; p1 = anew;
        b3 = b2; b2 = b1; b1 = fe1;
        c1 = fe2;
        x1a = x1b; x1b = x1c; x1c = f1;
        x2a = x2b; x2b = f2;

        block_sync_lds();   // LDS-only barrier: RAW+WAR for Pb/E1b/E2b rings
    }

    if (VAR == 1) {
        #pragma unroll
        for (int off = 32; off > 0; off >>= 1) {
            acc0 += __shfl_down(acc0, off);
            acc1 += __shfl_down(acc1, off);
        }
        int wid = tid >> 6, lane = tid & 63;
        __syncthreads();
        if (lane == 0) { smr[wid][0] = acc0; smr[wid][1] = acc1; }
        __syncthreads();
        if (tid == 0) {
            float t0 = 0.f, t1 = 0.f;
            #pragma unroll
            for (int w = 0; w < NT / 64; ++w) { t0 += smr[w][0]; t1 += smr[w][1]; }
            long base = ((long)i * NTB + bx) * 2;
            partials[base + 0] = t0;
            partials[base + 1] = t1;
        }
    }
}

// one block (64 threads) per volume: sum NTB=64 partial pairs in double
__global__ void reduce_partials_kernel(const float* __restrict__ partials,
                                       int i0,
                                       double* __restrict__ sums) {
    int i = i0 + blockIdx.x;
    int t = threadIdx.x;    // 64
    long base = ((long)i * NTB + t) * 2;
    double v0 = (double)partials[base + 0];
    double v1 = (double)partials[base + 1];
    #pragma unroll
    for (int off = 32; off > 0; off >>= 1) {
        v0 += __shfl_down(v0, off);
        v1 += __shfl_down(v1, off);
    }
    if (t == 0) {
        sums[2 * i + 0] = v0;
        sums[2 * i + 1] = v1;
    }
}

__global__ void finalize_kernel(const double* __restrict__ sums,
                                float* __restrict__ out) {
    if (threadIdx.x == 0 && blockIdx.x == 0) {
        double acc = 0.0;
        #pragma unroll
        for (int i = 0; i < 4; ++i) {
            double tprec = (sums[2 * i + 0] + SMOOTHF) / (sums[2 * i + 1] + SMOOTHF);
            double tsens = (sums[2 * (i + 4) + 0] + SMOOTHF) / (sums[2 * (i + 4) + 1] + SMOOTHF);
            double cl = (2.0 * tprec * tsens + SMOOTHF) / (tprec + tsens + SMOOTHF);
            acc += cl;
        }
        out[0] = (float)(1.0 - acc * 0.25);
    }
}

extern "C" void kernel_launch(void* const* d_in, const int* in_sizes, int n_in,
                              void* d_out, int out_size, void* d_ws, size_t ws_size,
                              hipStream_t stream) {
    const float* net = (const float*)d_in[0];
    const int* tgt = (const int*)d_in[1];
    float* out = (float*)d_out;

    char* ws = (char*)d_ws;
    double* sums = (double*)ws;                      // 16 doubles
    float* partials = (float*)(ws + 256);            // 8*NTB*2 floats
    size_t head = 256 + (size_t)8 * NTB * 2 * sizeof(float);
    head = (head + 255) & ~(size_t)255;
    float* base = (float*)(ws + head);

    size_t perVol = (size_t)2 * V_ * sizeof(float);  // SKEL + E2 per volume
    int G = 1;
    if (ws_size >= head + perVol * 8) G = 8;
    else if (ws_size >= head + perVol * 4) G = 4;
    else if (ws_size >= head + perVol * 2) G = 2;

    dim3 blk(NT);
    dim3 grd(NTB, G);

    for (int i0 = 0; i0 < 8; i0 += G) {
        float* SKEL = base;
        float* E2buf = base + (size_t)G * V_;

        // A: src -> e2 volume + skel (iterations 0,1)
        fused_pair<0><<<grd, blk, 0, stream>>>(net, tgt, i0, nullptr, E2buf, SKEL, nullptr);
        // B: e2 -> (e3,e4 in LDS/regs), final skel in-register, reduce
        fused_pair<1><<<grd, blk, 0, stream>>>(net, tgt, i0, E2buf, nullptr, SKEL, partials);

        reduce_partials_kernel<<<G, 64, 0, stream>>>(partials, i0, sums);
    }

    finalize_kernel<<<1, 64, 0, stream>>>(sums, out);
}